// Round 12
// baseline (297.002 us; speedup 1.0000x reference)
//
#include <hip/hip_runtime.h>
#include <hip/hip_bf16.h>
#include <math.h>

// ---- problem constants ----
#define BB 2
#define HH 16
#define NN 1024
#define CC 1024
#define DD 64
#define NPAST 8192
#define NANCH 1024
#define CBUD 4096
#define NKEEP 3072
#define NCAND 8192
#define BH 32

// tiled bf16 layout: K-chunk tile = 128 rows x 64 k x 2B = 16384 bytes
#define TILEB 16384

// ---- d_out layout (floats) ----
#define OUT_SZ   (BB*NN*CC)
#define KNEW_OFF ((size_t)OUT_SZ)
#define KNEW_SZ  ((size_t)BH*CBUD*DD)
#define VNEW_OFF (KNEW_OFF + KNEW_SZ)
#define AVG_OFF  (VNEW_OFF + KNEW_SZ)

// ---- workspace layout (float offsets), with overlays ----
#define WS_KF   ((size_t)0)            // 2097152 f
#define WS_VF   ((size_t)2097152)     // 2097152 f
#define WS_VTS  ((size_t)0)            // bf16 V^T swizzled tiles overlay (after gather)
#define WS_XT   ((size_t)4194304)     // x tiled bf16: 1048576 f
#define WS_OT   ((size_t)4194304)     // o tiled bf16 (overlay XT)
#define WS_WQVT ((size_t)5242880)     // w(Q,V) tiled bf16: 1048576 f
#define WS_WPT  ((size_t)5242880)     // proj_w tiled bf16 (overlay)
#define WS_QB   ((size_t)6291456)     // q bf16 (PRE-SCALED by 0.125*log2e): 1048576 f
#define WS_MD   ((size_t)7340032)     // 2048 f
#define WS_SC   ((size_t)7342080)     // scores 262144 f
#define WS_BS   ((size_t)7604224)     // 64 f
#define WS_SEL  ((size_t)7604288)     // 98304 ints -> ends 7702592
#define WS_MDP  ((size_t)7702592)     // mean_dir partials [32][8][64] = 16384 f
#define WS_BSP  ((size_t)7718976)     // score-sum partials [32][8] = 256 f
#define WS_KTS  ((size_t)7719232)     // OPTIONAL bf16 K swizzled tiles: 4194304 f (guarded by ws_size)
// base end = 7719232 floats = 30.9 MB; with KTS = 11913536 f = 47.7 MB

typedef __attribute__((ext_vector_type(8))) short short8;
typedef __attribute__((ext_vector_type(4))) float f32x4;

typedef unsigned int __attribute__((address_space(3))) lds_uint;
typedef unsigned int __attribute__((address_space(1))) glb_uint;

__device__ __forceinline__ void gload16(const void* g, void* l) {
    __builtin_amdgcn_global_load_lds((const glb_uint*)g, (lds_uint*)l, 16, 0, 0);
}

__device__ inline unsigned short f2bf(float f) {
    unsigned u = __float_as_uint(f);
    unsigned r = (u + 0x7FFFu + ((u >> 16) & 1u)) >> 16;
    return (unsigned short)r;
}
__device__ inline unsigned cvtpk(float a, float b) {
    __hip_bfloat162 h = __float22bfloat162_rn(make_float2(a, b));
    return *reinterpret_cast<unsigned*>(&h);
}
__device__ __forceinline__ float fexp2(float x) {
#if __has_builtin(__builtin_amdgcn_exp2f)
    return __builtin_amdgcn_exp2f(x);
#else
    return exp2f(x);
#endif
}

// ============================================================
// merged converter: blocks <1024: x -> xt; >=1024: qkv_w(Q,V) -> wqvt
// ============================================================
__global__ __launch_bounds__(256) void conv_xw(const float* __restrict__ x,
                                               const float* __restrict__ qw,
                                               unsigned short* __restrict__ xt,
                                               unsigned short* __restrict__ wqvt)
{
    int bid = blockIdx.x;
    int gid = (bid & 1023) * 256 + threadIdx.x;
    int r = gid >> 7, k0 = (gid & 127) * 8;
    const float* src;
    unsigned short* dst;
    int srow;
    if (bid < 1024) { src = x;  dst = xt;   srow = r; }
    else            { src = qw; dst = wqvt; srow = (r < 1024) ? r : r + 1024; }
    float4 a = *(const float4*)&src[(size_t)srow * 1024 + k0];
    float4 b = *(const float4*)&src[(size_t)srow * 1024 + k0 + 4];
    uint4 u;
    u.x = cvtpk(a.x, a.y); u.y = cvtpk(a.z, a.w);
    u.z = cvtpk(b.x, b.y); u.w = cvtpk(b.z, b.w);
    size_t tile = (size_t)(r >> 7) * 16 + (k0 >> 6);
    int inner = (((r & 127) * 128 + (k0 & 63) * 2)) ^ ((r & 7) << 4);
    *(uint4*)((char*)dst + tile * TILEB + inner) = u;
}

// ============================================================
// fp32 GEMM for K-third (ranking path). 64x32 tiles, grid
// (32,32)=1024 blocks (4/CU, 16 waves/CU). Per-thread 4x2.
// Per-output-element accumulation sequence BIT-IDENTICAL to r11
// (kk-ordered 16-chunk hierarchical sum). Double-buffered LDS.
// ============================================================
__global__ __launch_bounds__(256) void kf_gemm(const float* __restrict__ x,
                                               const float* __restrict__ w,
                                               const float* __restrict__ bias,
                                               float* __restrict__ ws)
{
    __shared__ float As[2][16][68];
    __shared__ float Bs[2][16][36];
    int tid = threadIdx.x;
    int m0 = blockIdx.y * 64;
    int n0 = blockIdx.x * 32;
    int tx = tid & 15, ty = tid >> 4;     // 16 cols x 2, 16 rows x 4
    int lr = tid >> 2;                     // A loader: rows 0..63
    int lk = (tid & 3) * 4;                // k 0,4,8,12
    int lrB = tid >> 3;                    // B loader: rows 0..31
    int lkB = (tid & 7) * 2;               // k 0,2,..,14
    float acc[4][2] = {{0.f}};

    // prologue: load + stage k0=0 into buf 0
    {
        float4 a = *(const float4*)&x[(size_t)(m0 + lr) * CC + lk];
        float2 b = *(const float2*)&w[(size_t)(1024 + n0 + lrB) * CC + lkB];
        As[0][lk+0][lr] = a.x; As[0][lk+1][lr] = a.y; As[0][lk+2][lr] = a.z; As[0][lk+3][lr] = a.w;
        Bs[0][lkB+0][lrB] = b.x; Bs[0][lkB+1][lrB] = b.y;
    }
    __syncthreads();

    int cur = 0;
    for (int k0 = 0; k0 < CC; k0 += 16) {
        float4 a; float2 b;
        bool more = (k0 + 16 < CC);
        if (more) {
            a = *(const float4*)&x[(size_t)(m0 + lr) * CC + k0 + 16 + lk];
            b = *(const float2*)&w[(size_t)(1024 + n0 + lrB) * CC + k0 + 16 + lkB];
        }
        float tacc[4][2] = {{0.f}};
        #pragma unroll
        for (int kk = 0; kk < 16; ++kk) {
            float4 a4 = *(const float4*)&As[cur][kk][ty*4];
            float2 b2 = *(const float2*)&Bs[cur][kk][tx*2];
            float av[4] = {a4.x, a4.y, a4.z, a4.w};
            float bv[2] = {b2.x, b2.y};
            #pragma unroll
            for (int i = 0; i < 4; ++i)
                #pragma unroll
                for (int j = 0; j < 2; ++j)
                    tacc[i][j] += av[i] * bv[j];
        }
        #pragma unroll
        for (int i = 0; i < 4; ++i)
            #pragma unroll
            for (int j = 0; j < 2; ++j)
                acc[i][j] += tacc[i][j];
        if (more) {
            As[cur^1][lk+0][lr] = a.x; As[cur^1][lk+1][lr] = a.y;
            As[cur^1][lk+2][lr] = a.z; As[cur^1][lk+3][lr] = a.w;
            Bs[cur^1][lkB+0][lrB] = b.x; Bs[cur^1][lkB+1][lrB] = b.y;
        }
        __syncthreads();
        cur ^= 1;
    }

    int cn0 = n0 + tx * 2;                // 0..1022, even
    int h = cn0 >> 6, dd0 = cn0 & 63;     // 2 consecutive cols stay in one h
    float2 b2 = *(const float2*)&bias[1024 + cn0];
    float* kf = ws + WS_KF;
    #pragma unroll
    for (int i = 0; i < 4; ++i) {
        int m = m0 + ty * 4 + i;
        int b1 = m >> 10, n = m & 1023;
        float2 t;
        t.x = acc[i][0] + b2.x; t.y = acc[i][1] + b2.y;
        *(float2*)&kf[(((size_t)b1*HH + h)*NN + n)*DD + dd0] = t;
    }
}

// ============================================================
// bf16 MFMA GEMM, 128x128 tile, BK=64. MODE 0: QV epilogue
// (Q -> bf16 qb PRE-SCALED, V -> fp32 vf). MODE 1: proj -> dout.
// ============================================================
template<int MODE>
__global__ __launch_bounds__(256) void mfma_gemm(const unsigned short* __restrict__ At,
                                                 const unsigned short* __restrict__ Bt,
                                                 const float* __restrict__ bias,
                                                 float* __restrict__ outp)
{
    __shared__ char lds[131072];
    int tid = threadIdx.x;
    int w = tid >> 6, lane = tid & 63;
    int g = lane >> 4, r16 = lane & 15;
    int wr = w >> 1, wc = w & 1;
    int bm = blockIdx.y, bn = blockIdx.x;
    const int KB = 16;
    const float QSCL = 0.125f * 1.44269504089f;

    f32x4 acc[4][4];
    #pragma unroll
    for (int i = 0; i < 4; ++i)
        #pragma unroll
        for (int j = 0; j < 4; ++j) acc[i][j] = 0.f;

    const char* Abase = (const char*)At + (size_t)bm * KB * TILEB;
    const char* Bbase = (const char*)Bt + (size_t)bn * KB * TILEB;

    #pragma unroll
    for (int i = 0; i < 4; ++i) {
        gload16(Abase + (size_t)w*4096 + i*1024 + lane*16, lds + w*4096 + i*1024);
        gload16(Bbase + (size_t)w*4096 + i*1024 + lane*16, lds + TILEB + w*4096 + i*1024);
    }
    asm volatile("s_waitcnt vmcnt(0)" ::: "memory");
    __syncthreads();

    int cur = 0;
    for (int kb = 0; kb < KB; ++kb) {
        char* Acur = lds + cur * (2*TILEB);
        char* Bcur = Acur + TILEB;
        if (kb + 1 < KB) {
            char* Anxt = lds + (cur ^ 1) * (2*TILEB);
            char* Bnxt = Anxt + TILEB;
            const char* an = Abase + (size_t)(kb+1)*TILEB + w*4096;
            const char* bsrc = Bbase + (size_t)(kb+1)*TILEB + w*4096;
            #pragma unroll
            for (int i = 0; i < 4; ++i) {
                gload16(an + i*1024 + lane*16, Anxt + w*4096 + i*1024);
                gload16(bsrc + i*1024 + lane*16, Bnxt + w*4096 + i*1024);
            }
        }
        short8 a0[4], a1[4], b0[4], b1[4];
        #pragma unroll
        for (int mi = 0; mi < 4; ++mi) {
            int row = wr*64 + mi*16 + r16;
            int sw = (row & 7) << 4;
            a0[mi] = *(const short8*)(Acur + ((row*128 + g*16) ^ sw));
            a1[mi] = *(const short8*)(Acur + ((row*128 + 64 + g*16) ^ sw));
        }
        #pragma unroll
        for (int ni = 0; ni < 4; ++ni) {
            int row = wc*64 + ni*16 + r16;
            int sw = (row & 7) << 4;
            b0[ni] = *(const short8*)(Bcur + ((row*128 + g*16) ^ sw));
            b1[ni] = *(const short8*)(Bcur + ((row*128 + 64 + g*16) ^ sw));
        }
        __builtin_amdgcn_s_setprio(1);
        #pragma unroll
        for (int mi = 0; mi < 4; ++mi)
            #pragma unroll
            for (int ni = 0; ni < 4; ++ni) {
                acc[mi][ni] = __builtin_amdgcn_mfma_f32_16x16x32_bf16(a0[mi], b0[ni], acc[mi][ni], 0, 0, 0);
                acc[mi][ni] = __builtin_amdgcn_mfma_f32_16x16x32_bf16(a1[mi], b1[ni], acc[mi][ni], 0, 0, 0);
            }
        __builtin_amdgcn_s_setprio(0);
        asm volatile("s_waitcnt vmcnt(0)" ::: "memory");
        __syncthreads();
        cur ^= 1;
    }

    int nq = bn*128 + wc*64;
    float bv[4];
    #pragma unroll
    for (int ni = 0; ni < 4; ++ni) {
        int n = nq + ni*16 + r16;
        bv[ni] = (MODE == 0) ? bias[(n < 1024) ? n : (n + 1024)] : bias[n];
    }
    #pragma unroll
    for (int mi = 0; mi < 4; ++mi) {
        #pragma unroll
        for (int rr = 0; rr < 4; ++rr) {
            int ml = wr*64 + mi*16 + 4*g + rr;
            int mg = bm*128 + ml;
            int bb = mg >> 10, tok = mg & 1023;
            #pragma unroll
            for (int ni = 0; ni < 4; ++ni) {
                int n = nq + ni*16 + r16;
                float v = acc[mi][ni][rr] + bv[ni];
                if (MODE == 0) {
                    if (n < 1024) {
                        unsigned short* qb = (unsigned short*)(outp + WS_QB);
                        int hh = n >> 6, d = n & 63;
                        qb[(((size_t)bb*16 + hh)*1024 + tok)*64 + d] = f2bf(v * QSCL);
                    } else {
                        float* vf = outp + WS_VF;
                        int hh = (n - 1024) >> 6, d = n & 63;
                        vf[(((size_t)bb*16 + hh)*1024 + tok)*64 + d] = v;
                    }
                } else {
                    outp[(size_t)mg*1024 + n] = v;
                }
            }
        }
    }
}

// ============================================================
// mean_dir / scores partials
// ============================================================
__global__ __launch_bounds__(256) void meandir_part(const float* __restrict__ past_k,
                                                    float* __restrict__ ws)
{
    int bh = blockIdx.x, seg = blockIdx.y, tid = threadIdx.x;
    const float* kpast = past_k + (size_t)bh * NPAST * DD;
    const float* knew  = ws + WS_KF + (size_t)bh * NN * DD;
    float dir[64];
    #pragma unroll
    for (int i = 0; i < 64; ++i) dir[i] = 0.f;

    int j0 = seg * 1024;
    for (int jj = tid; jj < 1024; jj += 256) {
        int pos = NANCH + j0 + jj;
        const float* row = (pos < NPAST) ? (kpast + (size_t)pos * DD)
                                         : (knew + (size_t)(pos - NPAST) * DD);
        float v[64]; float ss = 0.f;
        #pragma unroll
        for (int g = 0; g < 16; ++g) {
            float4 t = *(const float4*)&row[g*4];
            v[4*g]=t.x; v[4*g+1]=t.y; v[4*g+2]=t.z; v[4*g+3]=t.w;
            ss += t.x*t.x + t.y*t.y + t.z*t.z + t.w*t.w;
        }
        float inv = 1.0f / (sqrtf(ss) + 1e-6f);
        #pragma unroll
        for (int i = 0; i < 64; ++i) dir[i] += v[i] * inv;
    }
    #pragma unroll
    for (int i = 0; i < 64; ++i)
        for (int off = 32; off; off >>= 1) dir[i] += __shfl_xor(dir[i], off);

    __shared__ float sdir[4][64];
    int lane = tid & 63, wid = tid >> 6;
    if (lane == 0) {
        #pragma unroll
        for (int i = 0; i < 64; ++i) sdir[wid][i] = dir[i];
    }
    __syncthreads();
    if (tid < 64) {
        float s = sdir[0][tid] + sdir[1][tid] + sdir[2][tid] + sdir[3][tid];
        ws[WS_MDP + ((size_t)bh*8 + seg)*DD + tid] = s;
    }
}

__global__ void meandir_red(float* __restrict__ ws)
{
    int bh = blockIdx.x, tid = threadIdx.x;
    float s = 0.f;
    #pragma unroll
    for (int seg = 0; seg < 8; ++seg)
        s += ws[WS_MDP + ((size_t)bh*8 + seg)*DD + tid];
    ws[WS_MD + (size_t)bh*DD + tid] = s * (1.0f / (float)NCAND);
}

__global__ __launch_bounds__(256) void scores_part(const float* __restrict__ past_k,
                                                   float* __restrict__ ws)
{
    __shared__ float md[64];
    __shared__ float sred[4];
    int bh = blockIdx.x, seg = blockIdx.y, tid = threadIdx.x;
    if (tid < 64) md[tid] = ws[WS_MD + (size_t)bh*DD + tid];
    __syncthreads();
    const float* kpast = past_k + (size_t)bh * NPAST * DD;
    const float* knew  = ws + WS_KF + (size_t)bh * NN * DD;
    float ssum = 0.f;
    int j0 = seg * 1024;
    for (int jj = tid; jj < 1024; jj += 256) {
        int j = j0 + jj;
        int pos = NANCH + j;
        const float* row = (pos < NPAST) ? (kpast + (size_t)pos * DD)
                                         : (knew + (size_t)(pos - NPAST) * DD);
        float ss = 0.f, dp = 0.f;
        #pragma unroll
        for (int g = 0; g < 16; ++g) {
            float4 t = *(const float4*)&row[g*4];
            ss += t.x*t.x + t.y*t.y + t.z*t.z + t.w*t.w;
            dp += t.x*md[4*g] + t.y*md[4*g+1] + t.z*md[4*g+2] + t.w*md[4*g+3];
        }
        float sc = dp / (sqrtf(ss) + 1e-6f);
        ws[WS_SC + (size_t)bh*NCAND + j] = sc;
        ssum += sc;
    }
    for (int off = 32; off; off >>= 1) ssum += __shfl_xor(ssum, off);
    int lane = tid & 63, wid = tid >> 6;
    if (lane == 0) sred[wid] = ssum;
    __syncthreads();
    if (tid == 0)
        ws[WS_BSP + (size_t)bh*8 + seg] = sred[0] + sred[1] + sred[2] + sred[3];
}

// ============================================================
// topk: byte-histogram radix threshold + stable compaction.
// avg_scores folded in (block 0).
// ============================================================
__global__ __launch_bounds__(1024) void topk_k(float* __restrict__ ws, int* __restrict__ sel,
                                               float* __restrict__ dout)
{
    __shared__ unsigned keys[NCAND];
    __shared__ int hist[256];
    __shared__ int red[16];
    __shared__ int red2[16];
    __shared__ float fred[16];
    __shared__ int bcast;
    __shared__ unsigned bbyte;
    int bh = blockIdx.x, tid = threadIdx.x;
    int lane = tid & 63, wid = tid >> 6;

    if (bh == 0) {
        float v = (tid < 256) ? ws[WS_BSP + tid] : 0.f;
        for (int off = 32; off; off >>= 1) v += __shfl_xor(v, off);
        if (lane == 0) fred[wid] = v;
        __syncthreads();
        if (tid == 0) {
            float s = 0.f;
            for (int i = 0; i < 16; ++i) s += fred[i];
            dout[AVG_OFF] = s * (1.0f / ((float)BH * (float)NCAND));
        }
        __syncthreads();
    }

    for (int j = tid; j < NCAND; j += 1024) {
        unsigned u = __float_as_uint(ws[WS_SC + (size_t)bh*NCAND + j]);
        u ^= (u & 0x80000000u) ? 0xFFFFFFFFu : 0x80000000u;
        keys[j] = u;
    }
    __syncthreads();

    int rem = NKEEP;
    unsigned prefix = 0;
    #pragma unroll
    for (int pass = 0; pass < 4; ++pass) {
        int shift = 24 - 8*pass;
        if (tid < 256) hist[tid] = 0;
        __syncthreads();
        unsigned himask = (pass == 0) ? 0u : (0xFFFFFFFFu << (shift + 8));
        for (int j = tid; j < NCAND; j += 1024) {
            unsigned k = keys[j];
            if ((k & himask) == prefix)
                atomicAdd(&hist[(k >> shift) & 255], 1);
        }
        __syncthreads();
        if (tid == 0) {
            int cum = 0, b = 0;
            for (; b < 255; ++b) {
                if (rem <= cum + hist[b]) break;
                cum += hist[b];
            }
            bcast = cum;
            bbyte = (unsigned)b;
        }
        __syncthreads();
        rem -= bcast;
        prefix |= (bbyte << shift);
        __syncthreads();
    }
    unsigned T = prefix;

    {
        int cnt = 0;
        for (int j = tid; j < NCAND; j += 1024) cnt += (int)(keys[j] < T);
        for (int off = 32; off; off >>= 1) cnt += __shfl_xor(cnt, off);
        if (lane == 0) red[wid] = cnt;
        __syncthreads();
        if (tid == 0) { int c = 0; for (int i = 0; i < 16; ++i) c += red[i]; bcast = c; }
        __syncthreads();
    }
    int c_less = bcast;
    int ttie = NKEEP - c_less;

    int base = tid * 8;
    unsigned kv[8]; int lcnt = 0, ecnt = 0;
    #pragma unroll
    for (int i = 0; i < 8; ++i) {
        kv[i] = keys[base + i];
        lcnt += (int)(kv[i] < T);
        ecnt += (int)(kv[i] == T);
    }
    int li = lcnt, ei = ecnt;
    for (int off = 1; off < 64; off <<= 1) {
        int tl = __shfl_up(li, off);
        int te = __shfl_up(ei, off);
        if (lane >= off) { li += tl; ei += te; }
    }
    __syncthreads();
    if (lane == 63) { red[wid] = li; red2[wid] = ei; }
    __syncthreads();
    int lb = 0, eb = 0;
    for (int w = 0; w < wid; ++w) { lb += red[w]; eb += red2[w]; }
    lb += li - lcnt; eb += ei - ecnt;
    #pragma unroll
    for (int i = 0; i < 8; ++i) {
        bool less = kv[i] < T, eq = kv[i] == T;
        if (less || (eq && eb < ttie)) {
            int pos = lb + (eb < ttie ? eb : ttie);
            sel[(size_t)bh*NKEEP + pos] = base + i;
        }
        lb += (int)less; eb += (int)eq;
    }
}

// ============================================================
// gather k_new / v_new (fp32, exact) into d_out
// ============================================================
__global__ __launch_bounds__(256) void gather_k(const float* __restrict__ past_k,
                                                const float* __restrict__ past_v,
                                                const float* __restrict__ ws,
                                                const int* __restrict__ sel,
                                                float* __restrict__ dout)
{
    int gid = blockIdx.x * 256 + threadIdx.x;
    int row = gid >> 4, lane = gid & 15;
    int bh = row >> 12, r = row & 4095;
    int pos = (r < NANCH) ? r : (NANCH + sel[(size_t)bh*NKEEP + (r - NANCH)]);
    const float *kr, *vr;
    if (pos < NPAST) {
        kr = past_k + ((size_t)bh*NPAST + pos) * DD;
        vr = past_v + ((size_t)bh*NPAST + pos) * DD;
    } else {
        kr = ws + WS_KF + ((size_t)bh*NN + (pos - NPAST)) * DD;
        vr = ws + WS_VF + ((size_t)bh*NN + (pos - NPAST)) * DD;
    }
    float4 kq = *(const float4*)&kr[lane*4];
    float4 vq = *(const float4*)&vr[lane*4];
    *(float4*)&dout[KNEW_OFF + ((size_t)bh*CBUD + r)*DD + lane*4] = kq;
    *(float4*)&dout[VNEW_OFF + ((size_t)bh*CBUD + r)*DD + lane*4] = vq;
}

// ============================================================
// merged: blocks [0,2048): V^T bf16 swizzled tiles from v_new;
// [2048, 2048+nkblk): k_new -> bf16 swizzled K tiles (KTS);
// rest: proj_w -> tiled bf16 (wpt).
// ============================================================
__global__ __launch_bounds__(256) void vtrans_conv(const float* __restrict__ dout,
                                                   unsigned short* __restrict__ vt,
                                                   const float* __restrict__ pw,
                                                   unsigned short* __restrict__ wpt,
                                                   unsigned short* __restrict__ ktp,
                                                   int nkblk)
{
    int bid = blockIdx.x;
    if (bid >= 2048 && bid < 2048 + nkblk) {
        int bid2 = bid - 2048;
        int bh = bid2 >> 6, kt = bid2 & 63;
        int tid = threadIdx.x;
        int r = tid >> 2, c4 = (tid & 3) * 16;
        const float* kn = dout + KNEW_OFF + ((size_t)bh*CBUD + kt*64 + r)*DD + c4;
        float4 f0 = *(const float4*)&kn[0];
        float4 f1 = *(const float4*)&kn[4];
        float4 f2 = *(const float4*)&kn[8];
        float4 f3 = *(const float4*)&kn[12];
        uint4 u0, u1;
        u0.x = cvtpk(f0.x,f0.y); u0.y = cvtpk(f0.z,f0.w);
        u0.z = cvtpk(f1.x,f1.y); u0.w = cvtpk(f1.z,f1.w);
        u1.x = cvtpk(f2.x,f2.y); u1.y = cvtpk(f2.z,f2.w);
        u1.z = cvtpk(f3.x,f3.y); u1.w = cvtpk(f3.z,f3.w);
        size_t tbase = ((size_t)bh*64 + kt) * 8192;
        int sw = (r & 7) << 4;
        *(uint4*)((char*)ktp + tbase + ((r*128 + c4*2)      ^ sw)) = u0;
        *(uint4*)((char*)ktp + tbase + ((r*128 + c4*2 + 16) ^ sw)) = u1;
        return;
    }
    if (bid >= 2048 + nkblk) {
        int gid = (bid - 2048 - nkblk) * 256 + threadIdx.x;
        int r = gid >> 7, k0 = (gid & 127) * 8;
        float4 a = *(const float4*)&pw[(size_t)r * 1024 + k0];
        float4 b = *(const float4*)&pw[(size_t)r * 1024 + k0 + 4];
        uint4 u;
        u.x = cvtpk(a.x, a.y); u.y = cvtpk(a.z, a.w);
        u.z = cvtpk(b.x, b.y); u.w = cvtpk(b.z, b.w);
        size_t tile = (size_t)(r >> 7) * 16 + (k0 >> 6);
        int inner = (((r & 127) * 128 + (k0 & 63) * 2)) ^ ((r & 7) << 4);
        *(uint4*)((char*)wpt + tile * TILEB + inner) = u;
        return;
    }
    __shared__ unsigned short S[64][65];
    int bh = bid >> 6, kt = bid & 63;
    int c0 = kt * 64;
    int tid = threadIdx.x;
    int r = tid >> 2, c4 = (tid & 3) * 16;
    const float* src = dout + VNEW_OFF + ((size_t)bh*CBUD + c0 + r)*DD + c4;
    #pragma unroll
    for (int i = 0; i < 4; ++i) {
        float4 f = *(const float4*)&src[i*4];
        S[r][c4 + i*4 + 0] = f2bf(f.x);
        S[r][c4 + i*4 + 1] = f2bf(f.y);
        S[r][c4 + i*4 + 2] = f2bf(f.z);
        S[r][c4 + i*4 + 3] = f2bf(f.w);
    }
    __syncthreads();
    int d = r, k4 = c4;
    uint4 u0, u1;
    u0.x = (unsigned)S[k4+0][d] | ((unsigned)S[k4+1][d] << 16);
    u0.y = (unsigned)S[k4+2][d] | ((unsigned)S[k4+3][d] << 16);
    u0.z = (unsigned)S[k4+4][d] | ((unsigned)S[k4+5][d] << 16);
    u0.w = (unsigned)S[k4+6][d] | ((unsigned)S[k4+7][d] << 16);
    u1.x = (unsigned)S[k4+8][d] | ((unsigned)S[k4+9][d] << 16);
    u1.y = (unsigned)S[k4+10][d] | ((unsigned)S[k4+11][d] << 16);
    u1.z = (unsigned)S[k4+12][d] | ((unsigned)S[k4+13][d] << 16);
    u1.w = (unsigned)S[k4+14][d] | ((unsigned)S[k4+15][d] << 16);
    size_t tbase = ((size_t)bh*64 + kt) * 8192;
    int sw = (d & 7) << 4;
    *(uint4*)((char*)vt + tbase + ((d*128 + k4*2)      ^ sw)) = u0;
    *(uint4*)((char*)vt + tbase + ((d*128 + k4*2 + 16) ^ sw)) = u1;
}

// ============================================================
// MFMA flash attention, swapped QK^T, fixed-max softmax, 128-key
// iterations, 1 barrier/128 keys. Hoisted LDS offsets.
// KTS=1: K tiles DMA'd via gload16 from pre-converted swizzled
// tiles. KTS=0: K reg-staged from fp32 k_new (legacy).
// ============================================================
template<int KTS>
__global__ __launch_bounds__(256) void attn_mfma(const unsigned short* __restrict__ qb,
                                                 const float* __restrict__ dout,
                                                 const unsigned short* __restrict__ vt,
                                                 const unsigned short* __restrict__ ktp,
                                                 unsigned short* __restrict__ ot)
{
    __shared__ char kls[2][2][8192];
    __shared__ char vls[2][2][8192];
    __shared__ char pls[4][2048];

    int orig = blockIdx.x;
    int bid = (orig & 7) * 64 + (orig >> 3);
    int bh = bid >> 4, qt = bid & 15;
    int b = bh >> 4, h = bh & 15;
    int tid = threadIdx.x;
    int w = tid >> 6, lane = tid & 63;
    int g = lane >> 4, r16 = lane & 15;
    int q0 = qt * 64 + w * 16;

    const unsigned short* qrow = qb + ((size_t)bh*NN + q0 + r16) * DD;
    short8 qa0 = *(const short8*)&qrow[8*g];
    short8 qa1 = *(const short8*)&qrow[32 + 8*g];

    const float* kf = dout + KNEW_OFF + (size_t)bh * CBUD * DD;
    const char* vtt = (const char*)vt + (size_t)bh * 64 * 8192;
    const char* ktt = (const char*)ktp + (size_t)bh * 64 * 8192;
    char* plw = pls[w];
    int psw = (r16 & 7) << 4;

    int ro[8];
    #pragma unroll
    for (int t4 = 0; t4 < 4; ++t4) {
        int row = 16*t4 + r16;
        ro[2*t4]   = (row*128 + g*16) ^ psw;
        ro[2*t4+1] = (row*128 + 64 + g*16) ^ psw;
    }
    int pwo[4];
    #pragma unroll
    for (int t4 = 0; t4 < 4; ++t4)
        pwo[t4] = (r16*128 + (16*t4 + 4*g)*2) ^ psw;
    int pro0 = (r16*128 + 16*g) ^ psw;
    int pro1 = (r16*128 + 64 + 16*g) ^ psw;

    int srA = tid >> 3, srB = srA + 32;
    int scb = (tid & 7) * 16;
    int d0  = scb >> 1;
    int sdA = (srA*128 + scb) ^ ((srA & 7) << 4);
    int sdB = (srB*128 + scb) ^ ((srB & 7) << 4);

    f32x4 accd[4];
    #pragma unroll
    for (int dt = 0; dt < 4; ++dt) accd[dt] = 0.f;
    float lsum = 0.f;

    {
        gload16(vtt + tid*16,         vls[0][0] + tid*16);
        gload16(vtt + 4096 + tid*16,  vls[0][0] + 4096 + tid*16);
        gload16(vtt + 8192 + tid*16,  vls[0][1] + tid*16);
        gload16(vtt + 12288 + tid*16, vls[0][1] + 4096 + tid*16);
        if (KTS) {
            gload16(ktt + tid*16,         kls[0][0] + tid*16);
            gload16(ktt + 4096 + tid*16,  kls[0][0] + 4096 + tid*16);
            gload16(ktt + 8192 + tid*16,  kls[0][1] + tid*16);
            gload16(ktt + 12288 + tid*16, kls[0][1] + 4096 + tid*16);
        } else {
            #pragma unroll
            for (int hh = 0; hh < 2; ++hh) {
                const float* ksA = kf + ((size_t)hh*64 + srA) * DD + d0;
                const float* ksB = kf + ((size_t)hh*64 + srB) * DD + d0;
                float4 a0 = *(const float4*)ksA, a1 = *(const float4*)(ksA + 4);
                float4 b0 = *(const float4*)ksB, b1 = *(const float4*)(ksB + 4);
                uint4 kuA, kuB;
                kuA.x = cvtpk(a0.x,a0.y); kuA.y = cvtpk(a0.z,a0.w);
                kuA.z = cvtpk(a1.x,a1.y); kuA.w = cvtpk(a1.z,a1.w);
                kuB.x = cvtpk(b0.x,b0.y); kuB.y = cvtpk(b0.z,b0.w);
                kuB.z = cvtpk(b1.x,b1.y); kuB.w = cvtpk(b1.z,b1.w);
                *(uint4*)&kls[0][hh][sdA] = kuA;
                *(uint4*)&kls[0][hh][sdB] = kuB;
            }
        }
    }
    __syncthreads();

    int cur = 0;
    for (int t = 0; t < 32; ++t) {
        float4 na0[2], na1[2], nb0[2], nb1[2];
        bool more = (t + 1 < 32);
        if (more) {
            int nt = 2*t + 2;
            const char* vsrc = vtt + (size_t)nt*8192;
            gload16(vsrc + tid*16,         vls[cur^1][0] + tid*16);
            gload16(vsrc + 4096 + tid*16,  vls[cur^1][0] + 4096 + tid*16);
            gload16(vsrc + 8192 + tid*16,  vls[cur^1][1] + tid*16);
            gload16(vsrc + 12288 + tid*16, vls[cur^1][1] + 4096 + tid*16);
            if (KTS) {
                const char* ksrc = ktt + (size_t)nt*8192;
                gload16(ksrc + tid*16,         kls[cur^1][0] + tid*16);
                gload16(ksrc + 4096 + tid*16,  kls[cur^1][0] + 4096 + tid*16);
                gload16(ksrc + 8192 + tid*16,  kls[cur^1][1] + tid*16);
                gload16(ksrc + 12288 + tid*16, kls[cur^1][1] + 4096 + tid*16);
            } else {
                #pragma unroll
                for (int hh = 0; hh < 2; ++hh) {
                    const float* ksA = kf + ((size_t)(nt+hh)*64 + srA) * DD + d0;
                    const float* ksB = kf + ((size_t)(nt+hh)*64 + srB) * DD + d0;
                    na0[hh] = *(const float4*)ksA; na1[hh] = *(const float4*)(ksA + 4);
                    nb0[hh] = *(const float4*)ksB; nb1[hh] = *(const float4*)(ksB + 4);
                }
            }
        }

        #pragma unroll
        for (int hh = 0; hh < 2; ++hh) {
            const char* kb = kls[cur][hh];
            f32x4 sacc[4];
            #pragma unroll
            for (int t4 = 0; t4 < 4; ++t4) sacc[t4] = 0.f;
            __builtin_amdgcn_s_setprio(1);
            #pragma unroll
            for (int t4 = 0; t4 < 4; ++t4) {
                short8 ka0 = *(const short8*)(kb + ro[2*t4]);
                short8 ka1 = *(const short8*)(kb + ro[2*t4+1]);
                sacc[t4] = __builtin_amdgcn_mfma_f32_16x16x32_bf16(ka0, qa0, sacc[t4], 0, 0, 0);
                sacc[t4] = __builtin_amdgcn_mfma_f32_16x16x32_bf16(ka1, qa1, sacc[t4], 0, 0, 0);
            }
            __builtin_amdgcn_s_setprio(0);

            float p[4][4];
            float ps = 0.f;
            #pragma unroll
            for (int t4 = 0; t4 < 4; ++t4) {
                p[t4][0] = fexp2(sacc[t4][0]);
                p[t4][1] = fexp2(sacc[t4][1]);
                p[t4][2] = fexp2(sacc[t4][2]);
                p[t4][3] = fexp2(sacc[t4][3]);
                ps += (p[t4][0] + p[t4][1]) + (p[t4][2] + p[t4][3]);
            }
            lsum += ps;
            #pragma unroll
            for (int t4 = 0; t4 < 4; ++t4) {
                uint2 u;
                u.x = cvtpk(p[t4][0], p[t4][1]);
                u.y = cvtpk(p[t4][2], p[t4][3]);
                *(uint2*)&plw[pwo[t4]] = u;
            }

            short8 pa0 = *(const short8*)&plw[pro0];
            short8 pa1 = *(const short8*)&plw[pro1];
            const char* vb = vls[cur][hh];
            __builtin_amdgcn_s_setprio(1);
            #pragma unroll
            for (int dt = 0; dt < 4; ++dt) {
                short8 vb0 = *(const short8*)(vb + ro[2*dt]);
                short8 vb1 = *(const short8*)(vb + ro[2*dt+1]);
                accd[dt] = __builtin_amdgcn_mfma_f32_16x16x32_bf16(pa0, vb0, accd[dt], 0, 0, 0);
                accd[dt] = __builtin_amdgcn_mfma_f32_16x16x32_bf16(pa1, vb1, accd[dt], 0, 0, 0);
            }
            __builtin_amdgcn_s_setprio(0);
        }

        if (more && !KTS) {
            #pragma unroll
            for (int hh = 0; hh < 2; ++hh) {
                uint4 kuA, kuB;
                kuA.x = cvtpk(na0[hh].x, na0[hh].y); kuA.y = cvtpk(na0[hh].z, na0[hh].w);
                kuA.z = cvtpk(na1[hh].x, na1[hh].y); kuA.w = cvtpk(na1[hh].z, na1[hh].w);
                kuB.x = cvtpk(nb0[hh].x, nb0[hh].y); kuB.y = cvtpk(nb0[hh].z, nb0[hh].w);
                kuB.z = cvtpk(nb1[hh].x, nb1[hh].y); kuB.w = cvtpk(nb1[hh].z, nb1[hh].w);
                *(uint4*)&kls[cur^1][hh][sdA] = kuA;
                *(uint4*)&kls[cur^1][hh][sdB] = kuB;
            }
        }
        __syncthreads();
        cur ^= 1;
    }

    lsum += __shfl_xor(lsum, 16);
    lsum += __shfl_xor(lsum, 32);
    float ivl = 1.0f / lsum;
    float iq[4];
    #pragma unroll
    for (int rr = 0; rr < 4; ++rr) iq[rr] = __shfl(ivl, 20*g + rr);
    #pragma unroll
    for (int dt = 0; dt < 4; ++dt) {
        #pragma unroll
        for (int rr = 0; rr < 4; ++rr) {
            int q = q0 + 4*g + rr;
            int mrow = b*1024 + q;
            int d = dt*16 + r16;
            size_t tile = (size_t)(mrow >> 7) * 16 + h;
            int inner = ((mrow & 127)*128 + d*2) ^ ((mrow & 7) << 4);
            *(unsigned short*)((char*)ot + tile*TILEB + inner) = f2bf(accd[dt][rr] * iq[rr]);
        }
    }
}

// ============================================================
extern "C" void kernel_launch(void* const* d_in, const int* in_sizes, int n_in,
                              void* d_out, int out_size, void* d_ws, size_t ws_size,
                              hipStream_t stream)
{
    (void)in_sizes; (void)n_in; (void)out_size;
    const float* x      = (const float*)d_in[0];
    const float* past_k = (const float*)d_in[1];
    const float* past_v = (const float*)d_in[2];
    const float* qkv_w  = (const float*)d_in[3];
    const float* qkv_b  = (const float*)d_in[4];
    const float* proj_w = (const float*)d_in[5];
    const float* proj_b = (const float*)d_in[6];
    float* out = (float*)d_out;
    float* ws  = (float*)d_ws;
    int*   sel = (int*)(ws + WS_SEL);
    unsigned short* xt   = (unsigned short*)(ws + WS_XT);
    unsigned short* wqvt = (unsigned short*)(ws + WS_WQVT);
    unsigned short* wpt  = (unsigned short*)(ws + WS_WPT);
    unsigned short* qbp  = (unsigned short*)(ws + WS_QB);
    unsigned short* vtp  = (unsigned short*)(ws + WS_VTS);
    unsigned short* otp  = (unsigned short*)(ws + WS_OT);
    unsigned short* ktp  = (unsigned short*)(ws + WS_KTS);

    int use_kts = (ws_size >= (size_t)(WS_KTS + 4194304) * sizeof(float)) ? 1 : 0;
    int nkblk = use_kts ? 2048 : 0;

    conv_xw<<<2048, 256, 0, stream>>>(x, qkv_w, xt, wqvt);
    kf_gemm<<<dim3(32, 32), 256, 0, stream>>>(x, qkv_w, qkv_b, ws);
    mfma_gemm<0><<<dim3(16, 16), 256, 0, stream>>>(xt, wqvt, qkv_b, ws);
    meandir_part<<<dim3(32, 8), 256, 0, stream>>>(past_k, ws);
    meandir_red<<<32, 64, 0, stream>>>(ws);
    scores_part<<<dim3(32, 8), 256, 0, stream>>>(past_k, ws);
    topk_k<<<32, 1024, 0, stream>>>(ws, sel, out);
    gather_k<<<8192, 256, 0, stream>>>(past_k, past_v, ws, sel, out);
    vtrans_conv<<<2048 + nkblk + 512, 256, 0, stream>>>(out, vtp, proj_w, wpt, ktp, nkblk);
    if (use_kts)
        attn_mfma<1><<<512, 256, 0, stream>>>(qbp, out, vtp, ktp, otp);
    else
        attn_mfma<0><<<512, 256, 0, stream>>>(qbp, out, vtp, ktp, otp);
    mfma_gemm<1><<<dim3(8, 16), 256, 0, stream>>>(otp, wpt, proj_b, out);
}

// Round 13
// 270.605 us; speedup vs baseline: 1.0975x; 1.0975x over previous
//
#include <hip/hip_runtime.h>
#include <hip/hip_bf16.h>
#include <math.h>

// ---- problem constants ----
#define BB 2
#define HH 16
#define NN 1024
#define CC 1024
#define DD 64
#define NPAST 8192
#define NANCH 1024
#define CBUD 4096
#define NKEEP 3072
#define NCAND 8192
#define BH 32

// tiled bf16 layout: K-chunk tile = 128 rows x 64 k x 2B = 16384 bytes
#define TILEB 16384

// ---- d_out layout (floats) ----
#define OUT_SZ   (BB*NN*CC)
#define KNEW_OFF ((size_t)OUT_SZ)
#define KNEW_SZ  ((size_t)BH*CBUD*DD)
#define VNEW_OFF (KNEW_OFF + KNEW_SZ)
#define AVG_OFF  (VNEW_OFF + KNEW_SZ)

// ---- workspace layout (float offsets), with overlays ----
#define WS_KF   ((size_t)0)            // 2097152 f
#define WS_VF   ((size_t)2097152)     // 2097152 f
#define WS_VTS  ((size_t)0)            // bf16 V^T swizzled tiles overlay (after gather)
#define WS_XT   ((size_t)4194304)     // x tiled bf16: 1048576 f
#define WS_OT   ((size_t)4194304)     // o tiled bf16 (overlay XT)
#define WS_WQVT ((size_t)5242880)     // w(Q,V) tiled bf16: 1048576 f
#define WS_WPT  ((size_t)5242880)     // proj_w tiled bf16 (overlay)
#define WS_QB   ((size_t)6291456)     // q bf16 (PRE-SCALED by 0.125*log2e): 1048576 f
#define WS_MD   ((size_t)7340032)     // 2048 f (unused now)
#define WS_SC   ((size_t)7342080)     // scores 262144 f
#define WS_BS   ((size_t)7604224)     // 64 f
#define WS_SEL  ((size_t)7604288)     // 98304 ints -> ends 7702592
#define WS_MDP  ((size_t)7702592)     // mean_dir partials [32][8][64] = 16384 f
#define WS_BSP  ((size_t)7718976)     // score-sum partials [32][8] = 256 f
#define WS_KTS  ((size_t)7719232)     // OPTIONAL bf16 K swizzled tiles: 4194304 f (guarded by ws_size)
// base end = 7719232 floats = 30.9 MB; with KTS = 11913536 f = 47.7 MB

typedef __attribute__((ext_vector_type(8))) short short8;
typedef __attribute__((ext_vector_type(4))) float f32x4;

typedef unsigned int __attribute__((address_space(3))) lds_uint;
typedef unsigned int __attribute__((address_space(1))) glb_uint;

__device__ __forceinline__ void gload16(const void* g, void* l) {
    __builtin_amdgcn_global_load_lds((const glb_uint*)g, (lds_uint*)l, 16, 0, 0);
}

__device__ inline unsigned short f2bf(float f) {
    unsigned u = __float_as_uint(f);
    unsigned r = (u + 0x7FFFu + ((u >> 16) & 1u)) >> 16;
    return (unsigned short)r;
}
__device__ inline unsigned cvtpk(float a, float b) {
    __hip_bfloat162 h = __float22bfloat162_rn(make_float2(a, b));
    return *reinterpret_cast<unsigned*>(&h);
}
__device__ __forceinline__ float fexp2(float x) {
#if __has_builtin(__builtin_amdgcn_exp2f)
    return __builtin_amdgcn_exp2f(x);
#else
    return exp2f(x);
#endif
}

// ============================================================
// FUSED: blocks [0,512): fp32 K-third GEMM (r11 body, 64x64,
// BK=16 double-buffered, bit-identical accumulation).
// blocks [512,1536): x -> xt tiled bf16.
// blocks [1536,2560): qkv_w(Q,V) -> wqvt tiled bf16.
// Conv blocks hide under kf's latency-bound execution.
// ============================================================
__global__ __launch_bounds__(256) void kf_conv(const float* __restrict__ x,
                                               const float* __restrict__ qw,
                                               const float* __restrict__ bias,
                                               float* __restrict__ ws,
                                               unsigned short* __restrict__ xt,
                                               unsigned short* __restrict__ wqvt)
{
    __shared__ float As[2][16][68];
    __shared__ float Bs[2][16][68];
    int bid = blockIdx.x;
    int tid = threadIdx.x;

    if (bid >= 512) {
        int cb = bid - 512;
        int gid = (cb & 1023) * 256 + tid;
        int r = gid >> 7, k0 = (gid & 127) * 8;
        const float* src;
        unsigned short* dst;
        int srow;
        if (cb < 1024) { src = x;  dst = xt;   srow = r; }
        else           { src = qw; dst = wqvt; srow = (r < 1024) ? r : r + 1024; }
        float4 a = *(const float4*)&src[(size_t)srow * 1024 + k0];
        float4 b = *(const float4*)&src[(size_t)srow * 1024 + k0 + 4];
        uint4 u;
        u.x = cvtpk(a.x, a.y); u.y = cvtpk(a.z, a.w);
        u.z = cvtpk(b.x, b.y); u.w = cvtpk(b.z, b.w);
        size_t tile = (size_t)(r >> 7) * 16 + (k0 >> 6);
        int inner = (((r & 127) * 128 + (k0 & 63) * 2)) ^ ((r & 7) << 4);
        *(uint4*)((char*)dst + tile * TILEB + inner) = u;
        return;
    }

    // ---- kf GEMM tile (r11 body) ----
    int m0 = (bid >> 4) * 64;
    int n0 = (bid & 15) * 64;
    int tx = tid & 15, ty = tid >> 4;
    int lr = tid >> 2;
    int lk = (tid & 3) * 4;
    float acc[4][4] = {{0.f}};

    {
        float4 a = *(const float4*)&x[(size_t)(m0 + lr) * CC + lk];
        float4 b = *(const float4*)&qw[(size_t)(1024 + n0 + lr) * CC + lk];
        As[0][lk+0][lr] = a.x; As[0][lk+1][lr] = a.y; As[0][lk+2][lr] = a.z; As[0][lk+3][lr] = a.w;
        Bs[0][lk+0][lr] = b.x; Bs[0][lk+1][lr] = b.y; Bs[0][lk+2][lr] = b.z; Bs[0][lk+3][lr] = b.w;
    }
    __syncthreads();

    int cur = 0;
    for (int k0 = 0; k0 < CC; k0 += 16) {
        float4 a, b;
        bool more = (k0 + 16 < CC);
        if (more) {
            a = *(const float4*)&x[(size_t)(m0 + lr) * CC + k0 + 16 + lk];
            b = *(const float4*)&qw[(size_t)(1024 + n0 + lr) * CC + k0 + 16 + lk];
        }
        float tacc[4][4] = {{0.f}};
        #pragma unroll
        for (int kk = 0; kk < 16; ++kk) {
            float4 a4 = *(const float4*)&As[cur][kk][ty*4];
            float4 b4 = *(const float4*)&Bs[cur][kk][tx*4];
            float av[4] = {a4.x, a4.y, a4.z, a4.w};
            float bv[4] = {b4.x, b4.y, b4.z, b4.w};
            #pragma unroll
            for (int i = 0; i < 4; ++i)
                #pragma unroll
                for (int j = 0; j < 4; ++j)
                    tacc[i][j] += av[i] * bv[j];
        }
        #pragma unroll
        for (int i = 0; i < 4; ++i)
            #pragma unroll
            for (int j = 0; j < 4; ++j)
                acc[i][j] += tacc[i][j];
        if (more) {
            As[cur^1][lk+0][lr] = a.x; As[cur^1][lk+1][lr] = a.y;
            As[cur^1][lk+2][lr] = a.z; As[cur^1][lk+3][lr] = a.w;
            Bs[cur^1][lk+0][lr] = b.x; Bs[cur^1][lk+1][lr] = b.y;
            Bs[cur^1][lk+2][lr] = b.z; Bs[cur^1][lk+3][lr] = b.w;
        }
        __syncthreads();
        cur ^= 1;
    }

    int cn0 = n0 + tx * 4;
    int h = cn0 >> 6, dd0 = cn0 & 63;
    float4 b4 = *(const float4*)&bias[1024 + cn0];
    float* kf = ws + WS_KF;
    #pragma unroll
    for (int i = 0; i < 4; ++i) {
        int m = m0 + ty * 4 + i;
        int b2 = m >> 10, n = m & 1023;
        float4 t;
        t.x = acc[i][0] + b4.x; t.y = acc[i][1] + b4.y;
        t.z = acc[i][2] + b4.z; t.w = acc[i][3] + b4.w;
        *(float4*)&kf[(((size_t)b2*HH + h)*NN + n)*DD + dd0] = t;
    }
}

// ============================================================
// bf16 MFMA GEMM, 128x128 tile, BK=64. MODE 0: QV epilogue
// (Q -> bf16 qb PRE-SCALED, V -> fp32 vf). MODE 1: proj -> dout.
// ============================================================
template<int MODE>
__global__ __launch_bounds__(256) void mfma_gemm(const unsigned short* __restrict__ At,
                                                 const unsigned short* __restrict__ Bt,
                                                 const float* __restrict__ bias,
                                                 float* __restrict__ outp)
{
    __shared__ char lds[131072];
    int tid = threadIdx.x;
    int w = tid >> 6, lane = tid & 63;
    int g = lane >> 4, r16 = lane & 15;
    int wr = w >> 1, wc = w & 1;
    int bm = blockIdx.y, bn = blockIdx.x;
    const int KB = 16;
    const float QSCL = 0.125f * 1.44269504089f;

    f32x4 acc[4][4];
    #pragma unroll
    for (int i = 0; i < 4; ++i)
        #pragma unroll
        for (int j = 0; j < 4; ++j) acc[i][j] = 0.f;

    const char* Abase = (const char*)At + (size_t)bm * KB * TILEB;
    const char* Bbase = (const char*)Bt + (size_t)bn * KB * TILEB;

    #pragma unroll
    for (int i = 0; i < 4; ++i) {
        gload16(Abase + (size_t)w*4096 + i*1024 + lane*16, lds + w*4096 + i*1024);
        gload16(Bbase + (size_t)w*4096 + i*1024 + lane*16, lds + TILEB + w*4096 + i*1024);
    }
    asm volatile("s_waitcnt vmcnt(0)" ::: "memory");
    __syncthreads();

    int cur = 0;
    for (int kb = 0; kb < KB; ++kb) {
        char* Acur = lds + cur * (2*TILEB);
        char* Bcur = Acur + TILEB;
        if (kb + 1 < KB) {
            char* Anxt = lds + (cur ^ 1) * (2*TILEB);
            char* Bnxt = Anxt + TILEB;
            const char* an = Abase + (size_t)(kb+1)*TILEB + w*4096;
            const char* bsrc = Bbase + (size_t)(kb+1)*TILEB + w*4096;
            #pragma unroll
            for (int i = 0; i < 4; ++i) {
                gload16(an + i*1024 + lane*16, Anxt + w*4096 + i*1024);
                gload16(bsrc + i*1024 + lane*16, Bnxt + w*4096 + i*1024);
            }
        }
        short8 a0[4], a1[4], b0[4], b1[4];
        #pragma unroll
        for (int mi = 0; mi < 4; ++mi) {
            int row = wr*64 + mi*16 + r16;
            int sw = (row & 7) << 4;
            a0[mi] = *(const short8*)(Acur + ((row*128 + g*16) ^ sw));
            a1[mi] = *(const short8*)(Acur + ((row*128 + 64 + g*16) ^ sw));
        }
        #pragma unroll
        for (int ni = 0; ni < 4; ++ni) {
            int row = wc*64 + ni*16 + r16;
            int sw = (row & 7) << 4;
            b0[ni] = *(const short8*)(Bcur + ((row*128 + g*16) ^ sw));
            b1[ni] = *(const short8*)(Bcur + ((row*128 + 64 + g*16) ^ sw));
        }
        __builtin_amdgcn_s_setprio(1);
        #pragma unroll
        for (int mi = 0; mi < 4; ++mi)
            #pragma unroll
            for (int ni = 0; ni < 4; ++ni) {
                acc[mi][ni] = __builtin_amdgcn_mfma_f32_16x16x32_bf16(a0[mi], b0[ni], acc[mi][ni], 0, 0, 0);
                acc[mi][ni] = __builtin_amdgcn_mfma_f32_16x16x32_bf16(a1[mi], b1[ni], acc[mi][ni], 0, 0, 0);
            }
        __builtin_amdgcn_s_setprio(0);
        asm volatile("s_waitcnt vmcnt(0)" ::: "memory");
        __syncthreads();
        cur ^= 1;
    }

    int nq = bn*128 + wc*64;
    float bv[4];
    #pragma unroll
    for (int ni = 0; ni < 4; ++ni) {
        int n = nq + ni*16 + r16;
        bv[ni] = (MODE == 0) ? bias[(n < 1024) ? n : (n + 1024)] : bias[n];
    }
    #pragma unroll
    for (int mi = 0; mi < 4; ++mi) {
        #pragma unroll
        for (int rr = 0; rr < 4; ++rr) {
            int ml = wr*64 + mi*16 + 4*g + rr;
            int mg = bm*128 + ml;
            int bb = mg >> 10, tok = mg & 1023;
            #pragma unroll
            for (int ni = 0; ni < 4; ++ni) {
                int n = nq + ni*16 + r16;
                float v = acc[mi][ni][rr] + bv[ni];
                if (MODE == 0) {
                    if (n < 1024) {
                        unsigned short* qb = (unsigned short*)(outp + WS_QB);
                        int hh = n >> 6, d = n & 63;
                        qb[(((size_t)bb*16 + hh)*1024 + tok)*64 + d] = f2bf(v * QSCL);
                    } else {
                        float* vf = outp + WS_VF;
                        int hh = (n - 1024) >> 6, d = n & 63;
                        vf[(((size_t)bb*16 + hh)*1024 + tok)*64 + d] = v;
                    }
                } else {
                    outp[(size_t)mg*1024 + n] = v;
                }
            }
        }
    }
}

// ============================================================
// mean_dir partials: grid (32 bh, 8 seg)
// ============================================================
__global__ __launch_bounds__(256) void meandir_part(const float* __restrict__ past_k,
                                                    float* __restrict__ ws)
{
    int bh = blockIdx.x, seg = blockIdx.y, tid = threadIdx.x;
    const float* kpast = past_k + (size_t)bh * NPAST * DD;
    const float* knew  = ws + WS_KF + (size_t)bh * NN * DD;
    float dir[64];
    #pragma unroll
    for (int i = 0; i < 64; ++i) dir[i] = 0.f;

    int j0 = seg * 1024;
    for (int jj = tid; jj < 1024; jj += 256) {
        int pos = NANCH + j0 + jj;
        const float* row = (pos < NPAST) ? (kpast + (size_t)pos * DD)
                                         : (knew + (size_t)(pos - NPAST) * DD);
        float v[64]; float ss = 0.f;
        #pragma unroll
        for (int g = 0; g < 16; ++g) {
            float4 t = *(const float4*)&row[g*4];
            v[4*g]=t.x; v[4*g+1]=t.y; v[4*g+2]=t.z; v[4*g+3]=t.w;
            ss += t.x*t.x + t.y*t.y + t.z*t.z + t.w*t.w;
        }
        float inv = 1.0f / (sqrtf(ss) + 1e-6f);
        #pragma unroll
        for (int i = 0; i < 64; ++i) dir[i] += v[i] * inv;
    }
    #pragma unroll
    for (int i = 0; i < 64; ++i)
        for (int off = 32; off; off >>= 1) dir[i] += __shfl_xor(dir[i], off);

    __shared__ float sdir[4][64];
    int lane = tid & 63, wid = tid >> 6;
    if (lane == 0) {
        #pragma unroll
        for (int i = 0; i < 64; ++i) sdir[wid][i] = dir[i];
    }
    __syncthreads();
    if (tid < 64) {
        float s = sdir[0][tid] + sdir[1][tid] + sdir[2][tid] + sdir[3][tid];
        ws[WS_MDP + ((size_t)bh*8 + seg)*DD + tid] = s;
    }
}

// ============================================================
// scores: inline mean_dir reduction (seg-ordered, bit-identical
// to the old meandir_red) then per-candidate scores.
// ============================================================
__global__ __launch_bounds__(256) void scores_part(const float* __restrict__ past_k,
                                                   float* __restrict__ ws)
{
    __shared__ float md[64];
    __shared__ float sred[4];
    int bh = blockIdx.x, seg = blockIdx.y, tid = threadIdx.x;
    if (tid < 64) {
        float s = 0.f;
        #pragma unroll
        for (int sg = 0; sg < 8; ++sg)
            s += ws[WS_MDP + ((size_t)bh*8 + sg)*DD + tid];
        md[tid] = s * (1.0f / (float)NCAND);
    }
    __syncthreads();
    const float* kpast = past_k + (size_t)bh * NPAST * DD;
    const float* knew  = ws + WS_KF + (size_t)bh * NN * DD;
    float ssum = 0.f;
    int j0 = seg * 1024;
    for (int jj = tid; jj < 1024; jj += 256) {
        int j = j0 + jj;
        int pos = NANCH + j;
        const float* row = (pos < NPAST) ? (kpast + (size_t)pos * DD)
                                         : (knew + (size_t)(pos - NPAST) * DD);
        float ss = 0.f, dp = 0.f;
        #pragma unroll
        for (int g = 0; g < 16; ++g) {
            float4 t = *(const float4*)&row[g*4];
            ss += t.x*t.x + t.y*t.y + t.z*t.z + t.w*t.w;
            dp += t.x*md[4*g] + t.y*md[4*g+1] + t.z*md[4*g+2] + t.w*md[4*g+3];
        }
        float sc = dp / (sqrtf(ss) + 1e-6f);
        ws[WS_SC + (size_t)bh*NCAND + j] = sc;
        ssum += sc;
    }
    for (int off = 32; off; off >>= 1) ssum += __shfl_xor(ssum, off);
    int lane = tid & 63, wid = tid >> 6;
    if (lane == 0) sred[wid] = ssum;
    __syncthreads();
    if (tid == 0)
        ws[WS_BSP + (size_t)bh*8 + seg] = sred[0] + sred[1] + sred[2] + sred[3];
}

// ============================================================
// topk: byte-histogram radix threshold + stable compaction.
// avg_scores folded in (block 0).
// ============================================================
__global__ __launch_bounds__(1024) void topk_k(float* __restrict__ ws, int* __restrict__ sel,
                                               float* __restrict__ dout)
{
    __shared__ unsigned keys[NCAND];
    __shared__ int hist[256];
    __shared__ int red[16];
    __shared__ int red2[16];
    __shared__ float fred[16];
    __shared__ int bcast;
    __shared__ unsigned bbyte;
    int bh = blockIdx.x, tid = threadIdx.x;
    int lane = tid & 63, wid = tid >> 6;

    if (bh == 0) {
        float v = (tid < 256) ? ws[WS_BSP + tid] : 0.f;
        for (int off = 32; off; off >>= 1) v += __shfl_xor(v, off);
        if (lane == 0) fred[wid] = v;
        __syncthreads();
        if (tid == 0) {
            float s = 0.f;
            for (int i = 0; i < 16; ++i) s += fred[i];
            dout[AVG_OFF] = s * (1.0f / ((float)BH * (float)NCAND));
        }
        __syncthreads();
    }

    for (int j = tid; j < NCAND; j += 1024) {
        unsigned u = __float_as_uint(ws[WS_SC + (size_t)bh*NCAND + j]);
        u ^= (u & 0x80000000u) ? 0xFFFFFFFFu : 0x80000000u;
        keys[j] = u;
    }
    __syncthreads();

    int rem = NKEEP;
    unsigned prefix = 0;
    #pragma unroll
    for (int pass = 0; pass < 4; ++pass) {
        int shift = 24 - 8*pass;
        if (tid < 256) hist[tid] = 0;
        __syncthreads();
        unsigned himask = (pass == 0) ? 0u : (0xFFFFFFFFu << (shift + 8));
        for (int j = tid; j < NCAND; j += 1024) {
            unsigned k = keys[j];
            if ((k & himask) == prefix)
                atomicAdd(&hist[(k >> shift) & 255], 1);
        }
        __syncthreads();
        if (tid == 0) {
            int cum = 0, b = 0;
            for (; b < 255; ++b) {
                if (rem <= cum + hist[b]) break;
                cum += hist[b];
            }
            bcast = cum;
            bbyte = (unsigned)b;
        }
        __syncthreads();
        rem -= bcast;
        prefix |= (bbyte << shift);
        __syncthreads();
    }
    unsigned T = prefix;

    {
        int cnt = 0;
        for (int j = tid; j < NCAND; j += 1024) cnt += (int)(keys[j] < T);
        for (int off = 32; off; off >>= 1) cnt += __shfl_xor(cnt, off);
        if (lane == 0) red[wid] = cnt;
        __syncthreads();
        if (tid == 0) { int c = 0; for (int i = 0; i < 16; ++i) c += red[i]; bcast = c; }
        __syncthreads();
    }
    int c_less = bcast;
    int ttie = NKEEP - c_less;

    int base = tid * 8;
    unsigned kv[8]; int lcnt = 0, ecnt = 0;
    #pragma unroll
    for (int i = 0; i < 8; ++i) {
        kv[i] = keys[base + i];
        lcnt += (int)(kv[i] < T);
        ecnt += (int)(kv[i] == T);
    }
    int li = lcnt, ei = ecnt;
    for (int off = 1; off < 64; off <<= 1) {
        int tl = __shfl_up(li, off);
        int te = __shfl_up(ei, off);
        if (lane >= off) { li += tl; ei += te; }
    }
    __syncthreads();
    if (lane == 63) { red[wid] = li; red2[wid] = ei; }
    __syncthreads();
    int lb = 0, eb = 0;
    for (int w = 0; w < wid; ++w) { lb += red[w]; eb += red2[w]; }
    lb += li - lcnt; eb += ei - ecnt;
    #pragma unroll
    for (int i = 0; i < 8; ++i) {
        bool less = kv[i] < T, eq = kv[i] == T;
        if (less || (eq && eb < ttie)) {
            int pos = lb + (eb < ttie ? eb : ttie);
            sel[(size_t)bh*NKEEP + pos] = base + i;
        }
        lb += (int)less; eb += (int)eq;
    }
}

// ============================================================
// gather k_new / v_new (fp32, exact) into d_out
// ============================================================
__global__ __launch_bounds__(256) void gather_k(const float* __restrict__ past_k,
                                                const float* __restrict__ past_v,
                                                const float* __restrict__ ws,
                                                const int* __restrict__ sel,
                                                float* __restrict__ dout)
{
    int gid = blockIdx.x * 256 + threadIdx.x;
    int row = gid >> 4, lane = gid & 15;
    int bh = row >> 12, r = row & 4095;
    int pos = (r < NANCH) ? r : (NANCH + sel[(size_t)bh*NKEEP + (r - NANCH)]);
    const float *kr, *vr;
    if (pos < NPAST) {
        kr = past_k + ((size_t)bh*NPAST + pos) * DD;
        vr = past_v + ((size_t)bh*NPAST + pos) * DD;
    } else {
        kr = ws + WS_KF + ((size_t)bh*NN + (pos - NPAST)) * DD;
        vr = ws + WS_VF + ((size_t)bh*NN + (pos - NPAST)) * DD;
    }
    float4 kq = *(const float4*)&kr[lane*4];
    float4 vq = *(const float4*)&vr[lane*4];
    *(float4*)&dout[KNEW_OFF + ((size_t)bh*CBUD + r)*DD + lane*4] = kq;
    *(float4*)&dout[VNEW_OFF + ((size_t)bh*CBUD + r)*DD + lane*4] = vq;
}

// ============================================================
// merged: blocks [0,2048): V^T bf16 swizzled tiles from v_new;
// [2048, 2048+nkblk): k_new -> bf16 swizzled K tiles (KTS);
// rest: proj_w -> tiled bf16 (wpt).
// ============================================================
__global__ __launch_bounds__(256) void vtrans_conv(const float* __restrict__ dout,
                                                   unsigned short* __restrict__ vt,
                                                   const float* __restrict__ pw,
                                                   unsigned short* __restrict__ wpt,
                                                   unsigned short* __restrict__ ktp,
                                                   int nkblk)
{
    int bid = blockIdx.x;
    if (bid >= 2048 && bid < 2048 + nkblk) {
        int bid2 = bid - 2048;
        int bh = bid2 >> 6, kt = bid2 & 63;
        int tid = threadIdx.x;
        int r = tid >> 2, c4 = (tid & 3) * 16;
        const float* kn = dout + KNEW_OFF + ((size_t)bh*CBUD + kt*64 + r)*DD + c4;
        float4 f0 = *(const float4*)&kn[0];
        float4 f1 = *(const float4*)&kn[4];
        float4 f2 = *(const float4*)&kn[8];
        float4 f3 = *(const float4*)&kn[12];
        uint4 u0, u1;
        u0.x = cvtpk(f0.x,f0.y); u0.y = cvtpk(f0.z,f0.w);
        u0.z = cvtpk(f1.x,f1.y); u0.w = cvtpk(f1.z,f1.w);
        u1.x = cvtpk(f2.x,f2.y); u1.y = cvtpk(f2.z,f2.w);
        u1.z = cvtpk(f3.x,f3.y); u1.w = cvtpk(f3.z,f3.w);
        size_t tbase = ((size_t)bh*64 + kt) * 8192;
        int sw = (r & 7) << 4;
        *(uint4*)((char*)ktp + tbase + ((r*128 + c4*2)      ^ sw)) = u0;
        *(uint4*)((char*)ktp + tbase + ((r*128 + c4*2 + 16) ^ sw)) = u1;
        return;
    }
    if (bid >= 2048 + nkblk) {
        int gid = (bid - 2048 - nkblk) * 256 + threadIdx.x;
        int r = gid >> 7, k0 = (gid & 127) * 8;
        float4 a = *(const float4*)&pw[(size_t)r * 1024 + k0];
        float4 b = *(const float4*)&pw[(size_t)r * 1024 + k0 + 4];
        uint4 u;
        u.x = cvtpk(a.x, a.y); u.y = cvtpk(a.z, a.w);
        u.z = cvtpk(b.x, b.y); u.w = cvtpk(b.z, b.w);
        size_t tile = (size_t)(r >> 7) * 16 + (k0 >> 6);
        int inner = (((r & 127) * 128 + (k0 & 63) * 2)) ^ ((r & 7) << 4);
        *(uint4*)((char*)wpt + tile * TILEB + inner) = u;
        return;
    }
    __shared__ unsigned short S[64][65];
    int bh = bid >> 6, kt = bid & 63;
    int c0 = kt * 64;
    int tid = threadIdx.x;
    int r = tid >> 2, c4 = (tid & 3) * 16;
    const float* src = dout + VNEW_OFF + ((size_t)bh*CBUD + c0 + r)*DD + c4;
    #pragma unroll
    for (int i = 0; i < 4; ++i) {
        float4 f = *(const float4*)&src[i*4];
        S[r][c4 + i*4 + 0] = f2bf(f.x);
        S[r][c4 + i*4 + 1] = f2bf(f.y);
        S[r][c4 + i*4 + 2] = f2bf(f.z);
        S[r][c4 + i*4 + 3] = f2bf(f.w);
    }
    __syncthreads();
    int d = r, k4 = c4;
    uint4 u0, u1;
    u0.x = (unsigned)S[k4+0][d] | ((unsigned)S[k4+1][d] << 16);
    u0.y = (unsigned)S[k4+2][d] | ((unsigned)S[k4+3][d] << 16);
    u0.z = (unsigned)S[k4+4][d] | ((unsigned)S[k4+5][d] << 16);
    u0.w = (unsigned)S[k4+6][d] | ((unsigned)S[k4+7][d] << 16);
    u1.x = (unsigned)S[k4+8][d] | ((unsigned)S[k4+9][d] << 16);
    u1.y = (unsigned)S[k4+10][d] | ((unsigned)S[k4+11][d] << 16);
    u1.z = (unsigned)S[k4+12][d] | ((unsigned)S[k4+13][d] << 16);
    u1.w = (unsigned)S[k4+14][d] | ((unsigned)S[k4+15][d] << 16);
    size_t tbase = ((size_t)bh*64 + kt) * 8192;
    int sw = (d & 7) << 4;
    *(uint4*)((char*)vt + tbase + ((d*128 + k4*2)      ^ sw)) = u0;
    *(uint4*)((char*)vt + tbase + ((d*128 + k4*2 + 16) ^ sw)) = u1;
}

// ============================================================
// MFMA flash attention, swapped QK^T, fixed-max softmax, 128-key
// iterations, 1 barrier/128 keys. Hoisted LDS offsets.
// KTS=1: K tiles DMA'd via gload16 from pre-converted swizzled
// tiles. KTS=0: K reg-staged from fp32 k_new (legacy).
// ============================================================
template<int KTS>
__global__ __launch_bounds__(256) void attn_mfma(const unsigned short* __restrict__ qb,
                                                 const float* __restrict__ dout,
                                                 const unsigned short* __restrict__ vt,
                                                 const unsigned short* __restrict__ ktp,
                                                 unsigned short* __restrict__ ot)
{
    __shared__ char kls[2][2][8192];
    __shared__ char vls[2][2][8192];
    __shared__ char pls[4][2048];

    int orig = blockIdx.x;
    int bid = (orig & 7) * 64 + (orig >> 3);
    int bh = bid >> 4, qt = bid & 15;
    int b = bh >> 4, h = bh & 15;
    int tid = threadIdx.x;
    int w = tid >> 6, lane = tid & 63;
    int g = lane >> 4, r16 = lane & 15;
    int q0 = qt * 64 + w * 16;

    const unsigned short* qrow = qb + ((size_t)bh*NN + q0 + r16) * DD;
    short8 qa0 = *(const short8*)&qrow[8*g];
    short8 qa1 = *(const short8*)&qrow[32 + 8*g];

    const float* kf = dout + KNEW_OFF + (size_t)bh * CBUD * DD;
    const char* vtt = (const char*)vt + (size_t)bh * 64 * 8192;
    const char* ktt = (const char*)ktp + (size_t)bh * 64 * 8192;
    char* plw = pls[w];
    int psw = (r16 & 7) << 4;

    int ro[8];
    #pragma unroll
    for (int t4 = 0; t4 < 4; ++t4) {
        int row = 16*t4 + r16;
        ro[2*t4]   = (row*128 + g*16) ^ psw;
        ro[2*t4+1] = (row*128 + 64 + g*16) ^ psw;
    }
    int pwo[4];
    #pragma unroll
    for (int t4 = 0; t4 < 4; ++t4)
        pwo[t4] = (r16*128 + (16*t4 + 4*g)*2) ^ psw;
    int pro0 = (r16*128 + 16*g) ^ psw;
    int pro1 = (r16*128 + 64 + 16*g) ^ psw;

    int srA = tid >> 3, srB = srA + 32;
    int scb = (tid & 7) * 16;
    int d0  = scb >> 1;
    int sdA = (srA*128 + scb) ^ ((srA & 7) << 4);
    int sdB = (srB*128 + scb) ^ ((srB & 7) << 4);

    f32x4 accd[4];
    #pragma unroll
    for (int dt = 0; dt < 4; ++dt) accd[dt] = 0.f;
    float lsum = 0.f;

    {
        gload16(vtt + tid*16,         vls[0][0] + tid*16);
        gload16(vtt + 4096 + tid*16,  vls[0][0] + 4096 + tid*16);
        gload16(vtt + 8192 + tid*16,  vls[0][1] + tid*16);
        gload16(vtt + 12288 + tid*16, vls[0][1] + 4096 + tid*16);
        if (KTS) {
            gload16(ktt + tid*16,         kls[0][0] + tid*16);
            gload16(ktt + 4096 + tid*16,  kls[0][0] + 4096 + tid*16);
            gload16(ktt + 8192 + tid*16,  kls[0][1] + tid*16);
            gload16(ktt + 12288 + tid*16, kls[0][1] + 4096 + tid*16);
        } else {
            #pragma unroll
            for (int hh = 0; hh < 2; ++hh) {
                const float* ksA = kf + ((size_t)hh*64 + srA) * DD + d0;
                const float* ksB = kf + ((size_t)hh*64 + srB) * DD + d0;
                float4 a0 = *(const float4*)ksA, a1 = *(const float4*)(ksA + 4);
                float4 b0 = *(const float4*)ksB, b1 = *(const float4*)(ksB + 4);
                uint4 kuA, kuB;
                kuA.x = cvtpk(a0.x,a0.y); kuA.y = cvtpk(a0.z,a0.w);
                kuA.z = cvtpk(a1.x,a1.y); kuA.w = cvtpk(a1.z,a1.w);
                kuB.x = cvtpk(b0.x,b0.y); kuB.y = cvtpk(b0.z,b0.w);
                kuB.z = cvtpk(b1.x,b1.y); kuB.w = cvtpk(b1.z,b1.w);
                *(uint4*)&kls[0][hh][sdA] = kuA;
                *(uint4*)&kls[0][hh][sdB] = kuB;
            }
        }
    }
    __syncthreads();

    int cur = 0;
    for (int t = 0; t < 32; ++t) {
        float4 na0[2], na1[2], nb0[2], nb1[2];
        bool more = (t + 1 < 32);
        if (more) {
            int nt = 2*t + 2;
            const char* vsrc = vtt + (size_t)nt*8192;
            gload16(vsrc + tid*16,         vls[cur^1][0] + tid*16);
            gload16(vsrc + 4096 + tid*16,  vls[cur^1][0] + 4096 + tid*16);
            gload16(vsrc + 8192 + tid*16,  vls[cur^1][1] + tid*16);
            gload16(vsrc + 12288 + tid*16, vls[cur^1][1] + 4096 + tid*16);
            if (KTS) {
                const char* ksrc = ktt + (size_t)nt*8192;
                gload16(ksrc + tid*16,         kls[cur^1][0] + tid*16);
                gload16(ksrc + 4096 + tid*16,  kls[cur^1][0] + 4096 + tid*16);
                gload16(ksrc + 8192 + tid*16,  kls[cur^1][1] + tid*16);
                gload16(ksrc + 12288 + tid*16, kls[cur^1][1] + 4096 + tid*16);
            } else {
                #pragma unroll
                for (int hh = 0; hh < 2; ++hh) {
                    const float* ksA = kf + ((size_t)(nt+hh)*64 + srA) * DD + d0;
                    const float* ksB = kf + ((size_t)(nt+hh)*64 + srB) * DD + d0;
                    na0[hh] = *(const float4*)ksA; na1[hh] = *(const float4*)(ksA + 4);
                    nb0[hh] = *(const float4*)ksB; nb1[hh] = *(const float4*)(ksB + 4);
                }
            }
        }

        #pragma unroll
        for (int hh = 0; hh < 2; ++hh) {
            const char* kb = kls[cur][hh];
            f32x4 sacc[4];
            #pragma unroll
            for (int t4 = 0; t4 < 4; ++t4) sacc[t4] = 0.f;
            __builtin_amdgcn_s_setprio(1);
            #pragma unroll
            for (int t4 = 0; t4 < 4; ++t4) {
                short8 ka0 = *(const short8*)(kb + ro[2*t4]);
                short8 ka1 = *(const short8*)(kb + ro[2*t4+1]);
                sacc[t4] = __builtin_amdgcn_mfma_f32_16x16x32_bf16(ka0, qa0, sacc[t4], 0, 0, 0);
                sacc[t4] = __builtin_amdgcn_mfma_f32_16x16x32_bf16(ka1, qa1, sacc[t4], 0, 0, 0);
            }
            __builtin_amdgcn_s_setprio(0);

            float p[4][4];
            float ps = 0.f;
            #pragma unroll
            for (int t4 = 0; t4 < 4; ++t4) {
                p[t4][0] = fexp2(sacc[t4][0]);
                p[t4][1] = fexp2(sacc[t4][1]);
                p[t4][2] = fexp2(sacc[t4][2]);
                p[t4][3] = fexp2(sacc[t4][3]);
                ps += (p[t4][0] + p[t4][1]) + (p[t4][2] + p[t4][3]);
            }
            lsum += ps;
            #pragma unroll
            for (int t4 = 0; t4 < 4; ++t4) {
                uint2 u;
                u.x = cvtpk(p[t4][0], p[t4][1]);
                u.y = cvtpk(p[t4][2], p[t4][3]);
                *(uint2*)&plw[pwo[t4]] = u;
            }

            short8 pa0 = *(const short8*)&plw[pro0];
            short8 pa1 = *(const short8*)&plw[pro1];
            const char* vb = vls[cur][hh];
            __builtin_amdgcn_s_setprio(1);
            #pragma unroll
            for (int dt = 0; dt < 4; ++dt) {
                short8 vb0 = *(const short8*)(vb + ro[2*dt]);
                short8 vb1 = *(const short8*)(vb + ro[2*dt+1]);
                accd[dt] = __builtin_amdgcn_mfma_f32_16x16x32_bf16(pa0, vb0, accd[dt], 0, 0, 0);
                accd[dt] = __builtin_amdgcn_mfma_f32_16x16x32_bf16(pa1, vb1, accd[dt], 0, 0, 0);
            }
            __builtin_amdgcn_s_setprio(0);
        }

        if (more && !KTS) {
            #pragma unroll
            for (int hh = 0; hh < 2; ++hh) {
                uint4 kuA, kuB;
                kuA.x = cvtpk(na0[hh].x, na0[hh].y); kuA.y = cvtpk(na0[hh].z, na0[hh].w);
                kuA.z = cvtpk(na1[hh].x, na1[hh].y); kuA.w = cvtpk(na1[hh].z, na1[hh].w);
                kuB.x = cvtpk(nb0[hh].x, nb0[hh].y); kuB.y = cvtpk(nb0[hh].z, nb0[hh].w);
                kuB.z = cvtpk(nb1[hh].x, nb1[hh].y); kuB.w = cvtpk(nb1[hh].z, nb1[hh].w);
                *(uint4*)&kls[cur^1][hh][sdA] = kuA;
                *(uint4*)&kls[cur^1][hh][sdB] = kuB;
            }
        }
        __syncthreads();
        cur ^= 1;
    }

    lsum += __shfl_xor(lsum, 16);
    lsum += __shfl_xor(lsum, 32);
    float ivl = 1.0f / lsum;
    float iq[4];
    #pragma unroll
    for (int rr = 0; rr < 4; ++rr) iq[rr] = __shfl(ivl, 20*g + rr);
    #pragma unroll
    for (int dt = 0; dt < 4; ++dt) {
        #pragma unroll
        for (int rr = 0; rr < 4; ++rr) {
            int q = q0 + 4*g + rr;
            int mrow = b*1024 + q;
            int d = dt*16 + r16;
            size_t tile = (size_t)(mrow >> 7) * 16 + h;
            int inner = ((mrow & 127)*128 + d*2) ^ ((mrow & 7) << 4);
            *(unsigned short*)((char*)ot + tile*TILEB + inner) = f2bf(accd[dt][rr] * iq[rr]);
        }
    }
}

// ============================================================
extern "C" void kernel_launch(void* const* d_in, const int* in_sizes, int n_in,
                              void* d_out, int out_size, void* d_ws, size_t ws_size,
                              hipStream_t stream)
{
    (void)in_sizes; (void)n_in; (void)out_size;
    const float* x      = (const float*)d_in[0];
    const float* past_k = (const float*)d_in[1];
    const float* past_v = (const float*)d_in[2];
    const float* qkv_w  = (const float*)d_in[3];
    const float* qkv_b  = (const float*)d_in[4];
    const float* proj_w = (const float*)d_in[5];
    const float* proj_b = (const float*)d_in[6];
    float* out = (float*)d_out;
    float* ws  = (float*)d_ws;
    int*   sel = (int*)(ws + WS_SEL);
    unsigned short* xt   = (unsigned short*)(ws + WS_XT);
    unsigned short* wqvt = (unsigned short*)(ws + WS_WQVT);
    unsigned short* wpt  = (unsigned short*)(ws + WS_WPT);
    unsigned short* qbp  = (unsigned short*)(ws + WS_QB);
    unsigned short* vtp  = (unsigned short*)(ws + WS_VTS);
    unsigned short* otp  = (unsigned short*)(ws + WS_OT);
    unsigned short* ktp  = (unsigned short*)(ws + WS_KTS);

    int use_kts = (ws_size >= (size_t)(WS_KTS + 4194304) * sizeof(float)) ? 1 : 0;
    int nkblk = use_kts ? 2048 : 0;

    kf_conv<<<2560, 256, 0, stream>>>(x, qkv_w, qkv_b, ws, xt, wqvt);
    mfma_gemm<0><<<dim3(16, 16), 256, 0, stream>>>(xt, wqvt, qkv_b, ws);
    meandir_part<<<dim3(32, 8), 256, 0, stream>>>(past_k, ws);
    scores_part<<<dim3(32, 8), 256, 0, stream>>>(past_k, ws);
    topk_k<<<32, 1024, 0, stream>>>(ws, sel, out);
    gather_k<<<8192, 256, 0, stream>>>(past_k, past_v, ws, sel, out);
    vtrans_conv<<<2048 + nkblk + 512, 256, 0, stream>>>(out, vtp, proj_w, wpt, ktp, nkblk);
    if (use_kts)
        attn_mfma<1><<<512, 256, 0, stream>>>(qbp, out, vtp, ktp, otp);
    else
        attn_mfma<0><<<512, 256, 0, stream>>>(qbp, out, vtp, ktp, otp);
    mfma_gemm<1><<<dim3(8, 16), 256, 0, stream>>>(otp, wpt, proj_b, out);
}